// Round 11
// baseline (124.888 us; speedup 1.0000x reference)
//
#include <hip/hip_runtime.h>
#include <hip/hip_bf16.h>
#include <math.h>

#define NP 256
#define DD 65536

// ws float offsets
#define WS_SQ    65536          // 256
#define WS_KSUM  (65536 + 256)  // 256
#define WS_SIG   66048          // [0]=sigma [1]=1/(2s^2) [2]=1/s^2
// byte offsets
#define XBTF_BYTE_OFF  33818656u        // der B frags (d,k=i): 33,554,432 B
#define KBF_BYTE_OFF   67373088u        // der A frags (j,k=i): 131,072 B
#define WS_NEED_MID    67504160u
// gram K-partials: 256 slabs x 256x256 f32 = 64 MB, aliased into d_out's der
// region (written by fused_gram_cast, consumed by gram_reduce, then overwritten
// by der_mfma later in the same stream -- legal, deterministic).

typedef __attribute__((ext_vector_type(8))) short bf16x8;
typedef __attribute__((ext_vector_type(16))) float f32x16;

static __device__ __forceinline__ unsigned short f2bf(float f) {
    __hip_bfloat16 h = __float2bfloat16(f);
    return *reinterpret_cast<unsigned short*>(&h);
}
static __device__ __forceinline__ float bf2f(unsigned short u) {
    return __uint_as_float((unsigned)u << 16);
}
// read element (d, i) from XbTF fragment layout
static __device__ __forceinline__ float xtF(const unsigned short* __restrict__ XbTF,
                                            int d, int i) {
    return bf2f(XbTF[((size_t)((d >> 5) * 16 + (i >> 4))) * 512 +
                     (((i >> 3) & 1) * 32 + (d & 31)) * 8 + (i & 7)]);
}

// ---------------- fused cast+gram v2: 4 blocks/CU, P in d_out ----------------
// grid (2,2,256): (bx=j-tile, by=i-tile, z=K-split 256d). 256 thr, 4 waves,
// wave = 64x64 (acc[2][2] of 32x32), block tile 128x128, 4 sub-chunks of 64 d.
// Diag blocks (bx==by): B staging skipped (A==B); Bfrag is reused as the
// transpose buffer to emit XbTF for the block's 128 rows x 256-d slab.
__global__ __launch_bounds__(256) void fused_gram_cast(const float* __restrict__ X,
                                                       float* __restrict__ P,
                                                       unsigned short* __restrict__ XbTF) {
    __shared__ __align__(16) unsigned short Afrag[16 * 512];  // 16 KB: 4 ib x 4 k16
    __shared__ __align__(16) unsigned short Bfrag[16 * 512];  // 16 KB (or Tfrag on diag)
    const int t = threadIdx.x;
    const int lane = t & 63, w = t >> 6;
    const int wy = w >> 1, wx = w & 1;
    const int bx = blockIdx.x, by = blockIdx.y, z = blockIdx.z;
    const bool diag = (bx == by);
    const int rowA0 = by * 128, rowB0 = bx * 128;
    const int dbase = z * 256;
    const int lrow = t >> 1;          // 0..127
    const int lcol = (t & 1) * 32;    // 0 or 32

    f32x16 acc[2][2] = {};

#pragma unroll
    for (int sub = 0; sub < 4; ++sub) {
        const int d0 = dbase + sub * 64;
        {
            union { unsigned short u[32]; bf16x8 v[4]; } bva;
            const float4* srcA = (const float4*)&X[(size_t)(rowA0 + lrow) * DD + d0 + lcol];
#pragma unroll
            for (int q = 0; q < 8; q++) {
                float4 v = srcA[q];
                bva.u[q * 4 + 0] = f2bf(v.x); bva.u[q * 4 + 1] = f2bf(v.y);
                bva.u[q * 4 + 2] = f2bf(v.z); bva.u[q * 4 + 3] = f2bf(v.w);
            }
#pragma unroll
            for (int h = 0; h < 2; h++) {
                int ch = (lrow >> 5) * 4 + (lcol >> 4) + h;
                *(bf16x8*)&Afrag[ch * 512 + (lrow & 31) * 8]       = bva.v[h * 2];
                *(bf16x8*)&Afrag[ch * 512 + 256 + (lrow & 31) * 8] = bva.v[h * 2 + 1];
            }
            if (diag) {
                // transpose-scatter into Bfrag (16 chunks: 2 db x 8 i16)
#pragma unroll
                for (int e = 0; e < 32; e++) {
                    int dl = lcol + e;
                    int ch = (dl >> 5) * 8 + (lrow >> 4);
                    int slot = ((lrow >> 3) & 1) * 32 + (dl & 31);
                    Bfrag[ch * 512 + slot * 8 + (lrow & 7)] = bva.u[e];
                }
            } else {
                union { unsigned short u[32]; bf16x8 v[4]; } bvb;
                const float4* srcB = (const float4*)&X[(size_t)(rowB0 + lrow) * DD + d0 + lcol];
#pragma unroll
                for (int q = 0; q < 8; q++) {
                    float4 v = srcB[q];
                    bvb.u[q * 4 + 0] = f2bf(v.x); bvb.u[q * 4 + 1] = f2bf(v.y);
                    bvb.u[q * 4 + 2] = f2bf(v.z); bvb.u[q * 4 + 3] = f2bf(v.w);
                }
#pragma unroll
                for (int h = 0; h < 2; h++) {
                    int ch = (lrow >> 5) * 4 + (lcol >> 4) + h;
                    *(bf16x8*)&Bfrag[ch * 512 + (lrow & 31) * 8]       = bvb.v[h * 2];
                    *(bf16x8*)&Bfrag[ch * 512 + 256 + (lrow & 31) * 8] = bvb.v[h * 2 + 1];
                }
            }
        }
        __syncthreads();
        const unsigned short* Bsrc = diag ? Afrag : Bfrag;
#pragma unroll
        for (int ksi = 0; ksi < 4; ksi++) {
            bf16x8 a[2], b[2];
#pragma unroll
            for (int s = 0; s < 2; s++)
                a[s] = *(const bf16x8*)&Afrag[((wy * 2 + s) * 4 + ksi) * 512 + lane * 8];
#pragma unroll
            for (int u = 0; u < 2; u++)
                b[u] = *(const bf16x8*)&Bsrc[((wx * 2 + u) * 4 + ksi) * 512 + lane * 8];
#pragma unroll
            for (int s = 0; s < 2; s++)
#pragma unroll
                for (int u = 0; u < 2; u++)
                    acc[s][u] = __builtin_amdgcn_mfma_f32_32x32x16_bf16(a[s], b[u], acc[s][u], 0, 0, 0);
        }
        if (diag) {
            // coalesced XbTF write from Bfrag (16 chunks x 1 KB)
            int ch = t >> 4;             // 0..15
            int off = (t & 15) * 32;     // shorts
            int db_l = ch >> 3, i16_l = ch & 7;
            size_t gch = (size_t)((d0 >> 5) + db_l) * 16 + (rowA0 >> 4) + i16_l;
#pragma unroll
            for (int q = 0; q < 4; q++)
                *(bf16x8*)&XbTF[gch * 512 + off + q * 8] =
                    *(const bf16x8*)&Bfrag[ch * 512 + off + q * 8];
        }
        __syncthreads();
    }
    // ---- write P[z] quadrant ----
    const int hl = lane >> 5, lr = lane & 31;
    float* Pz = P + (size_t)z * 65536;
#pragma unroll
    for (int s = 0; s < 2; s++) {
        int ibase = by * 128 + wy * 64 + s * 32 + 4 * hl;
#pragma unroll
        for (int u = 0; u < 2; u++) {
            int jc = bx * 128 + wx * 64 + u * 32 + lr;
#pragma unroll
            for (int r = 0; r < 16; r++) {
                int ir = ibase + (r & 3) + 8 * (r >> 2);
                Pz[ir * 256 + jc] = acc[s][u][r];
            }
        }
    }
}

// ---------------- reduce 256 K-partials -> G ----------------
__global__ __launch_bounds__(256) void gram_reduce(const float* __restrict__ P,
                                                   float* __restrict__ G) {
    const int e4 = blockIdx.x * 256 + threadIdx.x;   // 16384 float4 slots
    const float4* P4 = (const float4*)P;
    float4 s = {0.f, 0.f, 0.f, 0.f};
#pragma unroll 8
    for (int z = 0; z < 256; z++) {
        float4 v = P4[(size_t)z * 16384 + e4];
        s.x += v.x; s.y += v.y; s.z += v.z; s.w += v.w;
    }
    ((float4*)G)[e4] = s;
}

// ---------------- median via 2-level histogram select, one launch ----------------
#define L1BINS 2048
__global__ __launch_bounds__(1024) void median_sigma_kernel(const float* __restrict__ G,
                                                            const float* __restrict__ EMA,
                                                            float* __restrict__ sq_ws,
                                                            float* __restrict__ sig,
                                                            float* __restrict__ sigma_out) {
    __shared__ unsigned hist[16][L1BINS];       // 128 KB, per-wave copies
    __shared__ unsigned scanw[48];
    __shared__ float sq_l[256];
    __shared__ float redf[32];
    __shared__ unsigned s_b0, s_b1, s_base0;
    __shared__ float s_v0, s_v1;
    const int t = threadIdx.x;
    const int lane = t & 63, wid = t >> 6;

    if (t < 256) { float v = G[t * (NP + 1)]; sq_l[t] = v; sq_ws[t] = v; }
    __syncthreads();
    const float4* G4 = (const float4*)G;

    float mn = 3.4e38f, mx = 0.f;
    for (int q = 0; q < 16; q++) {
        int idx4 = q * 1024 + t;
        float4 g = G4[idx4];
        int i = idx4 >> 6, jb = (idx4 * 4) & 255;
        float si = sq_l[i];
        float d0 = fmaxf(si + sq_l[jb + 0] - 2.f * g.x, 0.f);
        float d1 = fmaxf(si + sq_l[jb + 1] - 2.f * g.y, 0.f);
        float d2 = fmaxf(si + sq_l[jb + 2] - 2.f * g.z, 0.f);
        float d3 = fmaxf(si + sq_l[jb + 3] - 2.f * g.w, 0.f);
        mn = fminf(mn, fminf(fminf(d0, d1), fminf(d2, d3)));
        mx = fmaxf(mx, fmaxf(fmaxf(d0, d1), fmaxf(d2, d3)));
    }
    for (int off = 32; off; off >>= 1) {
        mn = fminf(mn, __shfl_down(mn, off));
        mx = fmaxf(mx, __shfl_down(mx, off));
    }
    if (lane == 0) { redf[wid] = mn; redf[16 + wid] = mx; }
    __syncthreads();
    if (t == 0) {
        float a = redf[0], b = redf[16];
        for (int i = 1; i < 16; i++) { a = fminf(a, redf[i]); b = fmaxf(b, redf[16 + i]); }
        redf[0] = a; redf[16] = b;
    }
    __syncthreads();
    const float mn0 = redf[0];
    const float rng = redf[16] - mn0;
    float med = mn0;

    if (rng > 0.f) {
        const float scale1 = (float)L1BINS * (1.f - 1e-6f) / rng;
        const float binw1 = rng / ((float)L1BINS * (1.f - 1e-6f));
        {
            uint4* h4 = (uint4*)hist;
            uint4 zz = {0u, 0u, 0u, 0u};
            for (int i = t; i < 16 * L1BINS / 4; i += 1024) h4[i] = zz;
        }
        __syncthreads();
        for (int q = 0; q < 16; q++) {
            int idx4 = q * 1024 + t;
            float4 g = G4[idx4];
            int i = idx4 >> 6, jb = (idx4 * 4) & 255;
            float si = sq_l[i];
            float dd[4];
            dd[0] = fmaxf(si + sq_l[jb + 0] - 2.f * g.x, 0.f);
            dd[1] = fmaxf(si + sq_l[jb + 1] - 2.f * g.y, 0.f);
            dd[2] = fmaxf(si + sq_l[jb + 2] - 2.f * g.z, 0.f);
            dd[3] = fmaxf(si + sq_l[jb + 3] - 2.f * g.w, 0.f);
#pragma unroll
            for (int e = 0; e < 4; e++) {
                int b = (int)((dd[e] - mn0) * scale1);
                b = min(max(b, 0), L1BINS - 1);
                atomicAdd(&hist[wid][b], 1u);
            }
        }
        __syncthreads();
        unsigned c0 = 0, c1 = 0;
#pragma unroll
        for (int wv = 0; wv < 16; wv++) { c0 += hist[wv][2 * t]; c1 += hist[wv][2 * t + 1]; }
        unsigned p = c0 + c1;
        unsigned v = p;
        for (int off = 1; off < 64; off <<= 1) {
            unsigned u = __shfl_up(v, off);
            if (lane >= off) v += u;
        }
        if (lane == 63) scanw[wid] = v;
        __syncthreads();
        if (t < 16) {
            unsigned s = 0;
            for (int i = 0; i <= t; i++) s += scanw[i];
            scanw[16 + t] = s;
        }
        __syncthreads();
        unsigned incl = v + ((wid == 0) ? 0u : scanw[16 + wid - 1]);
        unsigned excl = incl - p;
        if (excl <= 32767u && 32767u < excl + c0) { s_b0 = 2 * t;     s_base0 = excl; }
        else if (excl + c0 <= 32767u && 32767u < incl) { s_b0 = 2 * t + 1; s_base0 = excl + c0; }
        if (excl <= 32768u && 32768u < excl + c0) s_b1 = 2 * t;
        else if (excl + c0 <= 32768u && 32768u < incl) s_b1 = 2 * t + 1;
        __syncthreads();
        const unsigned b0 = s_b0, b1 = s_b1, base0 = s_base0;
        const float lo2 = mn0 + (float)b0 * binw1;
        const float span = (float)(b1 + 1 - b0) * binw1;
        const float scale2 = (float)L1BINS * (1.f - 1e-6f) / span;
        const float binw2 = span / ((float)L1BINS * (1.f - 1e-6f));
        {
            uint4* h4 = (uint4*)hist;
            uint4 zz = {0u, 0u, 0u, 0u};
            for (int i = t; i < 16 * L1BINS / 4; i += 1024) h4[i] = zz;
        }
        __syncthreads();
        for (int q = 0; q < 16; q++) {
            int idx4 = q * 1024 + t;
            float4 g = G4[idx4];
            int i = idx4 >> 6, jb = (idx4 * 4) & 255;
            float si = sq_l[i];
            float dd[4];
            dd[0] = fmaxf(si + sq_l[jb + 0] - 2.f * g.x, 0.f);
            dd[1] = fmaxf(si + sq_l[jb + 1] - 2.f * g.y, 0.f);
            dd[2] = fmaxf(si + sq_l[jb + 2] - 2.f * g.z, 0.f);
            dd[3] = fmaxf(si + sq_l[jb + 3] - 2.f * g.w, 0.f);
#pragma unroll
            for (int e = 0; e < 4; e++) {
                int b = (int)((dd[e] - mn0) * scale1);
                b = min(max(b, 0), L1BINS - 1);
                if (b >= (int)b0 && b <= (int)b1) {
                    int sb = (int)((dd[e] - lo2) * scale2);
                    sb = min(max(sb, 0), L1BINS - 1);
                    atomicAdd(&hist[wid][sb], 1u);
                }
            }
        }
        __syncthreads();
        const unsigned r0 = 32767u - base0, r1 = 32768u - base0;
        c0 = 0; c1 = 0;
#pragma unroll
        for (int wv = 0; wv < 16; wv++) { c0 += hist[wv][2 * t]; c1 += hist[wv][2 * t + 1]; }
        p = c0 + c1;
        v = p;
        for (int off = 1; off < 64; off <<= 1) {
            unsigned u = __shfl_up(v, off);
            if (lane >= off) v += u;
        }
        if (lane == 63) scanw[wid] = v;
        __syncthreads();
        if (t < 16) {
            unsigned s = 0;
            for (int i = 0; i <= t; i++) s += scanw[i];
            scanw[16 + t] = s;
        }
        __syncthreads();
        incl = v + ((wid == 0) ? 0u : scanw[16 + wid - 1]);
        excl = incl - p;
        if (excl <= r0 && r0 < excl + c0)           s_v0 = lo2 + ((float)(2 * t) + 0.5f) * binw2;
        else if (excl + c0 <= r0 && r0 < incl)      s_v0 = lo2 + ((float)(2 * t + 1) + 0.5f) * binw2;
        if (excl <= r1 && r1 < excl + c0)           s_v1 = lo2 + ((float)(2 * t) + 0.5f) * binw2;
        else if (excl + c0 <= r1 && r1 < incl)      s_v1 = lo2 + ((float)(2 * t + 1) + 0.5f) * binw2;
        __syncthreads();
        med = 0.5f * (s_v0 + s_v1);
    }

    if (t == 0) {
        float hh = med / (2.0f * logf((float)(NP + 1)));
        float s = sqrtf(hh);
        float e1 = EMA[1], e0 = EMA[0];
        s = e1 * s + (1.f - e1) * e0;
        sig[0] = s;
        sig[1] = 1.f / (2.f * s * s);
        sig[2] = 1.f / (s * s);
        *sigma_out = s;
    }
}

// ---------------- k from G,sq; kout fp32 + kbF (A-fragment layout) + ksum ----------------
__global__ __launch_bounds__(256) void kexp_kernel(const float* __restrict__ G,
                                                   const float* __restrict__ sq,
                                                   const float* __restrict__ sig,
                                                   float* __restrict__ kout,
                                                   unsigned short* __restrict__ kbF,
                                                   float* __restrict__ ksum) {
    int j = blockIdx.x, i = threadIdx.x;
    float d = fmaxf(sq[i] + sq[j] - 2.f * G[j * NP + i], 0.f);
    float kv = expf(-d * sig[1]);
    kout[j * NP + i] = kv;
    if (kbF) {
        int chunk = (j >> 5) * 16 + (i >> 4);
        int lanee = ((i >> 3) & 1) * 32 + (j & 31);
        kbF[chunk * 512 + lanee * 8 + (i & 7)] = f2bf(kv);
    }
    float s = kv;
    for (int off = 32; off > 0; off >>= 1) s += __shfl_down(s, off);
    __shared__ float wsum[4];
    int lane = i & 63, w = i >> 6;
    if (lane == 0) wsum[w] = s;
    __syncthreads();
    if (i == 0) ksum[j] = wsum[0] + wsum[1] + wsum[2] + wsum[3];
}

// ---------------- der: acc[2][2], 8 waves, 512 blocks; xtF epilogue ----------------
__global__ __launch_bounds__(512) void der_mfma(const unsigned short* __restrict__ kbF,
                                                const unsigned short* __restrict__ XbTF,
                                                const float* __restrict__ ksum,
                                                const float* __restrict__ sig,
                                                float* __restrict__ der) {
    const int t = threadIdx.x;
    const int lane = t & 63, w = t >> 6;
    const int wj = w >> 2, wd = w & 3;
    const int bx = blockIdx.x, by = blockIdx.y;

    f32x16 acc[2][2] = {};
    const unsigned short* pA[2];
    const unsigned short* pB[2];
#pragma unroll
    for (int s = 0; s < 2; s++)
        pA[s] = &kbF[(size_t)((by * 4 + wj * 2 + s) * 16) * 512 + lane * 8];
#pragma unroll
    for (int u = 0; u < 2; u++)
        pB[u] = &XbTF[(size_t)((bx * 8 + wd * 2 + u) * 16) * 512 + lane * 8];

#pragma unroll 4
    for (int i16 = 0; i16 < 16; i16++) {
        bf16x8 a[2], b[2];
#pragma unroll
        for (int s = 0; s < 2; s++) a[s] = *(const bf16x8*)(pA[s] + i16 * 512);
#pragma unroll
        for (int u = 0; u < 2; u++) b[u] = *(const bf16x8*)(pB[u] + i16 * 512);
#pragma unroll
        for (int s = 0; s < 2; s++)
#pragma unroll
            for (int u = 0; u < 2; u++)
                acc[s][u] = __builtin_amdgcn_mfma_f32_32x32x16_bf16(a[s], b[u], acc[s][u], 0, 0, 0);
    }
    const int hl = lane >> 5, lr = lane & 31;
    const float invs2 = sig[2];
#pragma unroll
    for (int u = 0; u < 2; u++) {
        const int dcol = bx * 256 + wd * 64 + u * 32 + lr;
#pragma unroll
        for (int s = 0; s < 2; s++) {
            const int jt = by * 128 + wj * 64 + s * 32;
#pragma unroll
            for (int q = 0; q < 4; q++) {
                int jq = jt + q * 8 + 4 * hl;
                float4 ks4 = *(const float4*)&ksum[jq];
                float x0 = xtF(XbTF, dcol, jq + 0);
                float x1 = xtF(XbTF, dcol, jq + 1);
                float x2 = xtF(XbTF, dcol, jq + 2);
                float x3 = xtF(XbTF, dcol, jq + 3);
                der[(size_t)(jq + 0) * DD + dcol] = (acc[s][u][q * 4 + 0] - ks4.x * x0) * invs2;
                der[(size_t)(jq + 1) * DD + dcol] = (acc[s][u][q * 4 + 1] - ks4.y * x1) * invs2;
                der[(size_t)(jq + 2) * DD + dcol] = (acc[s][u][q * 4 + 2] - ks4.z * x2) * invs2;
                der[(size_t)(jq + 3) * DD + dcol] = (acc[s][u][q * 4 + 3] - ks4.w * x3) * invs2;
            }
        }
    }
}

// ================= fallback fp32 path (ws too small) =================
__global__ __launch_bounds__(256) void gram_kernel(const float* __restrict__ X,
                                                   float* __restrict__ G) {
    __shared__ __align__(16) float As[32][72];
    __shared__ __align__(16) float Bs[32][72];
    const int i0 = blockIdx.x * 64;
    const int j0 = blockIdx.y * 64;
    const int k0 = blockIdx.z * 2048;
    const int t  = threadIdx.x;
    const int tx = t & 15, ty = t >> 4;
    float acc[4][4];
#pragma unroll
    for (int q = 0; q < 4; q++)
#pragma unroll
        for (int r = 0; r < 4; r++) acc[q][r] = 0.f;
    for (int kb = k0; kb < k0 + 2048; kb += 32) {
#pragma unroll
        for (int u = 0; u < 2; u++) {
            int f = t * 2 + u, row = f >> 3, c4 = (f & 7) * 4;
            float4 av = *(const float4*)&X[(size_t)(i0 + row) * DD + kb + c4];
            As[c4 + 0][row] = av.x; As[c4 + 1][row] = av.y;
            As[c4 + 2][row] = av.z; As[c4 + 3][row] = av.w;
            float4 bvv = *(const float4*)&X[(size_t)(j0 + row) * DD + kb + c4];
            Bs[c4 + 0][row] = bvv.x; Bs[c4 + 1][row] = bvv.y;
            Bs[c4 + 2][row] = bvv.z; Bs[c4 + 3][row] = bvv.w;
        }
        __syncthreads();
#pragma unroll
        for (int kk = 0; kk < 32; kk++) {
            float4 a4 = *(const float4*)&As[kk][ty * 4];
            float4 b4 = *(const float4*)&Bs[kk][tx * 4];
            acc[0][0] += a4.x * b4.x; acc[0][1] += a4.x * b4.y;
            acc[0][2] += a4.x * b4.z; acc[0][3] += a4.x * b4.w;
            acc[1][0] += a4.y * b4.x; acc[1][1] += a4.y * b4.y;
            acc[1][2] += a4.y * b4.z; acc[1][3] += a4.y * b4.w;
            acc[2][0] += a4.z * b4.x; acc[2][1] += a4.z * b4.y;
            acc[2][2] += a4.z * b4.z; acc[2][3] += a4.z * b4.w;
            acc[3][0] += a4.w * b4.x; acc[3][1] += a4.w * b4.y;
            acc[3][2] += a4.w * b4.z; acc[3][3] += a4.w * b4.w;
        }
        __syncthreads();
    }
#pragma unroll
    for (int q = 0; q < 4; q++)
#pragma unroll
        for (int r = 0; r < 4; r++)
            atomicAdd(&G[(size_t)(i0 + ty * 4 + q) * NP + j0 + tx * 4 + r], acc[q][r]);
}

__global__ __launch_bounds__(256) void der_kernel(const float* __restrict__ X,
                                                  const float* __restrict__ kmat,
                                                  const float* __restrict__ ksum,
                                                  const float* __restrict__ sig,
                                                  float* __restrict__ der) {
    const int j0 = blockIdx.y * 32;
    const int d0 = blockIdx.x * 512 + threadIdx.x * 2;
    const float invs2 = sig[2];
    float2 acc[32];
#pragma unroll
    for (int jl = 0; jl < 32; jl++) { acc[jl].x = 0.f; acc[jl].y = 0.f; }
    for (int i = 0; i < NP; i++) {
        float2 xv = *(const float2*)&X[(size_t)i * DD + d0];
        const float4* kr = (const float4*)&kmat[i * NP + j0];
#pragma unroll
        for (int q = 0; q < 8; q++) {
            float4 k4 = kr[q];
            acc[q * 4 + 0].x += k4.x * xv.x; acc[q * 4 + 0].y += k4.x * xv.y;
            acc[q * 4 + 1].x += k4.y * xv.x; acc[q * 4 + 1].y += k4.y * xv.y;
            acc[q * 4 + 2].x += k4.z * xv.x; acc[q * 4 + 2].y += k4.z * xv.y;
            acc[q * 4 + 3].x += k4.w * xv.x; acc[q * 4 + 3].y += k4.w * xv.y;
        }
    }
#pragma unroll
    for (int jl = 0; jl < 32; jl++) {
        int j = j0 + jl;
        float2 xj = *(const float2*)&X[(size_t)j * DD + d0];
        float ks = ksum[j];
        float2 o;
        o.x = (acc[jl].x - ks * xj.x) * invs2;
        o.y = (acc[jl].y - ks * xj.y) * invs2;
        *(float2*)&der[(size_t)j * DD + d0] = o;
    }
}

extern "C" void kernel_launch(void* const* d_in, const int* in_sizes, int n_in,
                              void* d_out, int out_size, void* d_ws, size_t ws_size,
                              hipStream_t stream) {
    const float* X   = (const float*)d_in[0];
    const float* EMA = (const float*)d_in[1];
    float* out = (float*)d_out;
    float* ws  = (float*)d_ws;

    float* G    = ws;
    float* sq   = ws + WS_SQ;
    float* ksum = ws + WS_KSUM;
    float* sig  = ws + WS_SIG;

    float* kout      = out;
    float* der       = out + NP * NP;
    float* sigma_out = out + out_size - 1;

    if (ws_size >= (size_t)WS_NEED_MID) {
        unsigned short* XbTF = (unsigned short*)((char*)d_ws + XBTF_BYTE_OFF);
        unsigned short* kbF  = (unsigned short*)((char*)d_ws + KBF_BYTE_OFF);
        float* P = der;   // 256 slabs x 256 KB = 64 MB, exactly the der region;
                          // fully rewritten every call before reduce reads it,
                          // then overwritten by der_mfma.

        fused_gram_cast<<<dim3(2, 2, 256), 256, 0, stream>>>(X, P, XbTF);
        gram_reduce<<<64, 256, 0, stream>>>(P, G);
        median_sigma_kernel<<<1, 1024, 0, stream>>>(G, EMA, sq, sig, sigma_out);
        kexp_kernel<<<NP, NP, 0, stream>>>(G, sq, sig, kout, kbF, ksum);
        der_mfma<<<dim3(256, 2), 512, 0, stream>>>(kbF, XbTF, ksum, sig, der);
    } else {
        hipMemsetAsync(G, 0, (size_t)NP * NP * sizeof(float), stream);
        gram_kernel<<<dim3(4, 4, 32), 256, 0, stream>>>(X, G);
        median_sigma_kernel<<<1, 1024, 0, stream>>>(G, EMA, sq, sig, sigma_out);
        kexp_kernel<<<NP, NP, 0, stream>>>(G, sq, sig, kout, nullptr, ksum);
        der_kernel<<<dim3(128, 8), 256, 0, stream>>>(X, kout, ksum, sig, der);
    }
}

// Round 12
// 102.728 us; speedup vs baseline: 1.2157x; 1.2157x over previous
//
#include <hip/hip_runtime.h>
#include <hip/hip_bf16.h>
#include <math.h>

#define NP 256
#define DD 65536

// ws float offsets
#define WS_SQ    65536          // 256
#define WS_KSUM  (65536 + 256)  // 256
#define WS_SIG   66048          // [0]=sigma [1]=1/(2s^2) [2]=1/s^2
// byte offsets
#define XBF_BYTE_OFF   264224u          // mid path only
#define XBTF_BYTE_OFF  33818656u        // der B frags (d,k=i): 33,554,432 B
#define KBF_BYTE_OFF   67373088u        // der A frags (j,k=i): 131,072 B
#define PART_BYTE_OFF  67504160u        // gram K-partials [64][256][256] f32: 16 MB
#define WS_NEED_MID    67504160u
#define WS_NEED_FULL   84281376u

typedef __attribute__((ext_vector_type(8))) short bf16x8;
typedef __attribute__((ext_vector_type(16))) float f32x16;

static __device__ __forceinline__ unsigned short f2bf(float f) {
    __hip_bfloat16 h = __float2bfloat16(f);
    return *reinterpret_cast<unsigned short*>(&h);
}
static __device__ __forceinline__ float bf2f(unsigned short u) {
    return __uint_as_float((unsigned)u << 16);
}
// read element (d, i) from XbTF fragment layout
static __device__ __forceinline__ float xtF(const unsigned short* __restrict__ XbTF,
                                            int d, int i) {
    return bf2f(XbTF[((size_t)((d >> 5) * 16 + (i >> 4))) * 512 +
                     (((i >> 3) & 1) * 32 + (d & 31)) * 8 + (i & 7)]);
}

// ---------------- fused cast+gram v3: z=64 (P=16MB), 512 thr = 2 waves/SIMD ----------------
// grid (2,2,64): (bx=j-tile, by=i-tile, z=K-split 1024d). 8 waves (wy=w>>2: 64-row
// half, wx=w&3: 32-col quarter), wave = 64x32 (acc[2] of 32x32). 16 sub-chunks of
// 64 d, 4 k16-steps each -> K-accumulation order identical to rounds 9-11 (G bitwise
// stable). Diag blocks (bx==by): skip B staging (A==B); Bfrag doubles as the
// transpose buffer emitting XbTF for the block's 128 rows x 1024-d slab.
__global__ __launch_bounds__(512) void fused_gram_cast(const float* __restrict__ X,
                                                       float* __restrict__ P,
                                                       unsigned short* __restrict__ XbTF) {
    __shared__ __align__(16) unsigned short Afrag[16 * 512];  // 16 KB: 4 rowgrp x 4 k16
    __shared__ __align__(16) unsigned short Bfrag[16 * 512];  // 16 KB (Tfrag on diag)
    const int t = threadIdx.x;
    const int lane = t & 63, w = t >> 6;
    const int wy = w >> 2, wx = w & 3;
    const int bx = blockIdx.x, by = blockIdx.y, z = blockIdx.z;
    const bool diag = (bx == by);
    const int rowA0 = by * 128, rowB0 = bx * 128;
    const int dbase = z * 1024;
    const int lrow = t >> 2;          // 0..127
    const int lcol = (t & 3) * 16;    // 0,16,32,48

    f32x16 acc[2] = {};

    for (int sub = 0; sub < 16; ++sub) {
        const int d0 = dbase + sub * 64;
        {
            union { unsigned short u[16]; bf16x8 v[2]; } bva;
            const float4* srcA = (const float4*)&X[(size_t)(rowA0 + lrow) * DD + d0 + lcol];
#pragma unroll
            for (int q = 0; q < 4; q++) {
                float4 v = srcA[q];
                bva.u[q * 4 + 0] = f2bf(v.x); bva.u[q * 4 + 1] = f2bf(v.y);
                bva.u[q * 4 + 2] = f2bf(v.z); bva.u[q * 4 + 3] = f2bf(v.w);
            }
            {
                int ch = (lrow >> 5) * 4 + (lcol >> 4);
                *(bf16x8*)&Afrag[ch * 512 + (lrow & 31) * 8]       = bva.v[0];
                *(bf16x8*)&Afrag[ch * 512 + 256 + (lrow & 31) * 8] = bva.v[1];
            }
            if (diag) {
                // transpose-scatter into Bfrag-as-Tfrag (16 chunks: 2 db x 8 i16)
#pragma unroll
                for (int e = 0; e < 16; e++) {
                    int dl = lcol + e;
                    int ch = (dl >> 5) * 8 + (lrow >> 4);
                    int slot = ((lrow >> 3) & 1) * 32 + (dl & 31);
                    Bfrag[ch * 512 + slot * 8 + (lrow & 7)] = bva.u[e];
                }
            } else {
                union { unsigned short u[16]; bf16x8 v[2]; } bvb;
                const float4* srcB = (const float4*)&X[(size_t)(rowB0 + lrow) * DD + d0 + lcol];
#pragma unroll
                for (int q = 0; q < 4; q++) {
                    float4 v = srcB[q];
                    bvb.u[q * 4 + 0] = f2bf(v.x); bvb.u[q * 4 + 1] = f2bf(v.y);
                    bvb.u[q * 4 + 2] = f2bf(v.z); bvb.u[q * 4 + 3] = f2bf(v.w);
                }
                int ch = (lrow >> 5) * 4 + (lcol >> 4);
                *(bf16x8*)&Bfrag[ch * 512 + (lrow & 31) * 8]       = bvb.v[0];
                *(bf16x8*)&Bfrag[ch * 512 + 256 + (lrow & 31) * 8] = bvb.v[1];
            }
        }
        __syncthreads();
        const unsigned short* Bsrc = diag ? Afrag : Bfrag;
#pragma unroll
        for (int ksi = 0; ksi < 4; ksi++) {
            bf16x8 a[2], b;
#pragma unroll
            for (int s = 0; s < 2; s++)
                a[s] = *(const bf16x8*)&Afrag[((wy * 2 + s) * 4 + ksi) * 512 + lane * 8];
            b = *(const bf16x8*)&Bsrc[(wx * 4 + ksi) * 512 + lane * 8];
#pragma unroll
            for (int s = 0; s < 2; s++)
                acc[s] = __builtin_amdgcn_mfma_f32_32x32x16_bf16(a[s], b, acc[s], 0, 0, 0);
        }
        if (diag) {
            // coalesced XbTF write from Tfrag: 16 chunks x 1 KB, 32 B/thread
            int ch = t >> 5;             // 0..15
            int off = (t & 31) * 16;     // shorts
            size_t gch = (size_t)((d0 >> 5) + (ch >> 3)) * 16 + (rowA0 >> 4) + (ch & 7);
#pragma unroll
            for (int q = 0; q < 2; q++)
                *(bf16x8*)&XbTF[gch * 512 + off + q * 8] =
                    *(const bf16x8*)&Bfrag[ch * 512 + off + q * 8];
        }
        __syncthreads();
    }
    // ---- write P[z] tile ----
    const int hl = lane >> 5, lr = lane & 31;
    float* Pz = P + (size_t)z * 65536;
    const int jc = bx * 128 + wx * 32 + lr;
#pragma unroll
    for (int s = 0; s < 2; s++) {
        int ibase = by * 128 + wy * 64 + s * 32 + 4 * hl;
#pragma unroll
        for (int r = 0; r < 16; r++) {
            int ir = ibase + (r & 3) + 8 * (r >> 2);
            Pz[ir * 256 + jc] = acc[s][r];
        }
    }
}

// ---------------- reduce 64 K-partials -> G ----------------
__global__ __launch_bounds__(256) void gram_reduce(const float* __restrict__ P,
                                                   float* __restrict__ G) {
    const int e4 = blockIdx.x * 256 + threadIdx.x;
    const float4* P4 = (const float4*)P;
    float4 s = {0.f, 0.f, 0.f, 0.f};
#pragma unroll 8
    for (int z = 0; z < 64; z++) {
        float4 v = P4[(size_t)z * 16384 + e4];
        s.x += v.x; s.y += v.y; s.z += v.z; s.w += v.w;
    }
    ((float4*)G)[e4] = s;
}

// ---------------- median via 2-level histogram select, one launch ----------------
#define L1BINS 2048
__global__ __launch_bounds__(1024) void median_sigma_kernel(const float* __restrict__ G,
                                                            const float* __restrict__ EMA,
                                                            float* __restrict__ sq_ws,
                                                            float* __restrict__ sig,
                                                            float* __restrict__ sigma_out) {
    __shared__ unsigned hist[16][L1BINS];       // 128 KB, per-wave copies
    __shared__ unsigned scanw[48];
    __shared__ float sq_l[256];
    __shared__ float redf[32];
    __shared__ unsigned s_b0, s_b1, s_base0;
    __shared__ float s_v0, s_v1;
    const int t = threadIdx.x;
    const int lane = t & 63, wid = t >> 6;

    if (t < 256) { float v = G[t * (NP + 1)]; sq_l[t] = v; sq_ws[t] = v; }
    __syncthreads();
    const float4* G4 = (const float4*)G;

    float mn = 3.4e38f, mx = 0.f;
    for (int q = 0; q < 16; q++) {
        int idx4 = q * 1024 + t;
        float4 g = G4[idx4];
        int i = idx4 >> 6, jb = (idx4 * 4) & 255;
        float si = sq_l[i];
        float d0 = fmaxf(si + sq_l[jb + 0] - 2.f * g.x, 0.f);
        float d1 = fmaxf(si + sq_l[jb + 1] - 2.f * g.y, 0.f);
        float d2 = fmaxf(si + sq_l[jb + 2] - 2.f * g.z, 0.f);
        float d3 = fmaxf(si + sq_l[jb + 3] - 2.f * g.w, 0.f);
        mn = fminf(mn, fminf(fminf(d0, d1), fminf(d2, d3)));
        mx = fmaxf(mx, fmaxf(fmaxf(d0, d1), fmaxf(d2, d3)));
    }
    for (int off = 32; off; off >>= 1) {
        mn = fminf(mn, __shfl_down(mn, off));
        mx = fmaxf(mx, __shfl_down(mx, off));
    }
    if (lane == 0) { redf[wid] = mn; redf[16 + wid] = mx; }
    __syncthreads();
    if (t == 0) {
        float a = redf[0], b = redf[16];
        for (int i = 1; i < 16; i++) { a = fminf(a, redf[i]); b = fmaxf(b, redf[16 + i]); }
        redf[0] = a; redf[16] = b;
    }
    __syncthreads();
    const float mn0 = redf[0];
    const float rng = redf[16] - mn0;
    float med = mn0;

    if (rng > 0.f) {
        const float scale1 = (float)L1BINS * (1.f - 1e-6f) / rng;
        const float binw1 = rng / ((float)L1BINS * (1.f - 1e-6f));
        {
            uint4* h4 = (uint4*)hist;
            uint4 zz = {0u, 0u, 0u, 0u};
            for (int i = t; i < 16 * L1BINS / 4; i += 1024) h4[i] = zz;
        }
        __syncthreads();
        for (int q = 0; q < 16; q++) {
            int idx4 = q * 1024 + t;
            float4 g = G4[idx4];
            int i = idx4 >> 6, jb = (idx4 * 4) & 255;
            float si = sq_l[i];
            float dd[4];
            dd[0] = fmaxf(si + sq_l[jb + 0] - 2.f * g.x, 0.f);
            dd[1] = fmaxf(si + sq_l[jb + 1] - 2.f * g.y, 0.f);
            dd[2] = fmaxf(si + sq_l[jb + 2] - 2.f * g.z, 0.f);
            dd[3] = fmaxf(si + sq_l[jb + 3] - 2.f * g.w, 0.f);
#pragma unroll
            for (int e = 0; e < 4; e++) {
                int b = (int)((dd[e] - mn0) * scale1);
                b = min(max(b, 0), L1BINS - 1);
                atomicAdd(&hist[wid][b], 1u);
            }
        }
        __syncthreads();
        unsigned c0 = 0, c1 = 0;
#pragma unroll
        for (int wv = 0; wv < 16; wv++) { c0 += hist[wv][2 * t]; c1 += hist[wv][2 * t + 1]; }
        unsigned p = c0 + c1;
        unsigned v = p;
        for (int off = 1; off < 64; off <<= 1) {
            unsigned u = __shfl_up(v, off);
            if (lane >= off) v += u;
        }
        if (lane == 63) scanw[wid] = v;
        __syncthreads();
        if (t < 16) {
            unsigned s = 0;
            for (int i = 0; i <= t; i++) s += scanw[i];
            scanw[16 + t] = s;
        }
        __syncthreads();
        unsigned incl = v + ((wid == 0) ? 0u : scanw[16 + wid - 1]);
        unsigned excl = incl - p;
        if (excl <= 32767u && 32767u < excl + c0) { s_b0 = 2 * t;     s_base0 = excl; }
        else if (excl + c0 <= 32767u && 32767u < incl) { s_b0 = 2 * t + 1; s_base0 = excl + c0; }
        if (excl <= 32768u && 32768u < excl + c0) s_b1 = 2 * t;
        else if (excl + c0 <= 32768u && 32768u < incl) s_b1 = 2 * t + 1;
        __syncthreads();
        const unsigned b0 = s_b0, b1 = s_b1, base0 = s_base0;
        const float lo2 = mn0 + (float)b0 * binw1;
        const float span = (float)(b1 + 1 - b0) * binw1;
        const float scale2 = (float)L1BINS * (1.f - 1e-6f) / span;
        const float binw2 = span / ((float)L1BINS * (1.f - 1e-6f));
        {
            uint4* h4 = (uint4*)hist;
            uint4 zz = {0u, 0u, 0u, 0u};
            for (int i = t; i < 16 * L1BINS / 4; i += 1024) h4[i] = zz;
        }
        __syncthreads();
        for (int q = 0; q < 16; q++) {
            int idx4 = q * 1024 + t;
            float4 g = G4[idx4];
            int i = idx4 >> 6, jb = (idx4 * 4) & 255;
            float si = sq_l[i];
            float dd[4];
            dd[0] = fmaxf(si + sq_l[jb + 0] - 2.f * g.x, 0.f);
            dd[1] = fmaxf(si + sq_l[jb + 1] - 2.f * g.y, 0.f);
            dd[2] = fmaxf(si + sq_l[jb + 2] - 2.f * g.z, 0.f);
            dd[3] = fmaxf(si + sq_l[jb + 3] - 2.f * g.w, 0.f);
#pragma unroll
            for (int e = 0; e < 4; e++) {
                int b = (int)((dd[e] - mn0) * scale1);
                b = min(max(b, 0), L1BINS - 1);
                if (b >= (int)b0 && b <= (int)b1) {
                    int sb = (int)((dd[e] - lo2) * scale2);
                    sb = min(max(sb, 0), L1BINS - 1);
                    atomicAdd(&hist[wid][sb], 1u);
                }
            }
        }
        __syncthreads();
        const unsigned r0 = 32767u - base0, r1 = 32768u - base0;
        c0 = 0; c1 = 0;
#pragma unroll
        for (int wv = 0; wv < 16; wv++) { c0 += hist[wv][2 * t]; c1 += hist[wv][2 * t + 1]; }
        p = c0 + c1;
        v = p;
        for (int off = 1; off < 64; off <<= 1) {
            unsigned u = __shfl_up(v, off);
            if (lane >= off) v += u;
        }
        if (lane == 63) scanw[wid] = v;
        __syncthreads();
        if (t < 16) {
            unsigned s = 0;
            for (int i = 0; i <= t; i++) s += scanw[i];
            scanw[16 + t] = s;
        }
        __syncthreads();
        incl = v + ((wid == 0) ? 0u : scanw[16 + wid - 1]);
        excl = incl - p;
        if (excl <= r0 && r0 < excl + c0)           s_v0 = lo2 + ((float)(2 * t) + 0.5f) * binw2;
        else if (excl + c0 <= r0 && r0 < incl)      s_v0 = lo2 + ((float)(2 * t + 1) + 0.5f) * binw2;
        if (excl <= r1 && r1 < excl + c0)           s_v1 = lo2 + ((float)(2 * t) + 0.5f) * binw2;
        else if (excl + c0 <= r1 && r1 < incl)      s_v1 = lo2 + ((float)(2 * t + 1) + 0.5f) * binw2;
        __syncthreads();
        med = 0.5f * (s_v0 + s_v1);
    }

    if (t == 0) {
        float hh = med / (2.0f * logf((float)(NP + 1)));
        float s = sqrtf(hh);
        float e1 = EMA[1], e0 = EMA[0];
        s = e1 * s + (1.f - e1) * e0;
        sig[0] = s;
        sig[1] = 1.f / (2.f * s * s);
        sig[2] = 1.f / (s * s);
        *sigma_out = s;
    }
}

// ---------------- k from G,sq; kout fp32 + kbF (A-fragment layout) + ksum ----------------
__global__ __launch_bounds__(256) void kexp_kernel(const float* __restrict__ G,
                                                   const float* __restrict__ sq,
                                                   const float* __restrict__ sig,
                                                   float* __restrict__ kout,
                                                   unsigned short* __restrict__ kbF,
                                                   float* __restrict__ ksum) {
    int j = blockIdx.x, i = threadIdx.x;
    float d = fmaxf(sq[i] + sq[j] - 2.f * G[j * NP + i], 0.f);
    float kv = expf(-d * sig[1]);
    kout[j * NP + i] = kv;
    if (kbF) {
        int chunk = (j >> 5) * 16 + (i >> 4);
        int lanee = ((i >> 3) & 1) * 32 + (j & 31);
        kbF[chunk * 512 + lanee * 8 + (i & 7)] = f2bf(kv);
    }
    float s = kv;
    for (int off = 32; off > 0; off >>= 1) s += __shfl_down(s, off);
    __shared__ float wsum[4];
    int lane = i & 63, w = i >> 6;
    if (lane == 0) wsum[w] = s;
    __syncthreads();
    if (i == 0) ksum[j] = wsum[0] + wsum[1] + wsum[2] + wsum[3];
}

// ---------------- der: acc[2][2], 8 waves, 512 blocks; xtF epilogue ----------------
__global__ __launch_bounds__(512) void der_mfma(const unsigned short* __restrict__ kbF,
                                                const unsigned short* __restrict__ XbTF,
                                                const float* __restrict__ ksum,
                                                const float* __restrict__ sig,
                                                float* __restrict__ der) {
    const int t = threadIdx.x;
    const int lane = t & 63, w = t >> 6;
    const int wj = w >> 2, wd = w & 3;
    const int bx = blockIdx.x, by = blockIdx.y;

    f32x16 acc[2][2] = {};
    const unsigned short* pA[2];
    const unsigned short* pB[2];
#pragma unroll
    for (int s = 0; s < 2; s++)
        pA[s] = &kbF[(size_t)((by * 4 + wj * 2 + s) * 16) * 512 + lane * 8];
#pragma unroll
    for (int u = 0; u < 2; u++)
        pB[u] = &XbTF[(size_t)((bx * 8 + wd * 2 + u) * 16) * 512 + lane * 8];

#pragma unroll 4
    for (int i16 = 0; i16 < 16; i16++) {
        bf16x8 a[2], b[2];
#pragma unroll
        for (int s = 0; s < 2; s++) a[s] = *(const bf16x8*)(pA[s] + i16 * 512);
#pragma unroll
        for (int u = 0; u < 2; u++) b[u] = *(const bf16x8*)(pB[u] + i16 * 512);
#pragma unroll
        for (int s = 0; s < 2; s++)
#pragma unroll
            for (int u = 0; u < 2; u++)
                acc[s][u] = __builtin_amdgcn_mfma_f32_32x32x16_bf16(a[s], b[u], acc[s][u], 0, 0, 0);
    }
    const int hl = lane >> 5, lr = lane & 31;
    const float invs2 = sig[2];
#pragma unroll
    for (int u = 0; u < 2; u++) {
        const int dcol = bx * 256 + wd * 64 + u * 32 + lr;
#pragma unroll
        for (int s = 0; s < 2; s++) {
            const int jt = by * 128 + wj * 64 + s * 32;
#pragma unroll
            for (int q = 0; q < 4; q++) {
                int jq = jt + q * 8 + 4 * hl;
                float4 ks4 = *(const float4*)&ksum[jq];
                float x0 = xtF(XbTF, dcol, jq + 0);
                float x1 = xtF(XbTF, dcol, jq + 1);
                float x2 = xtF(XbTF, dcol, jq + 2);
                float x3 = xtF(XbTF, dcol, jq + 3);
                der[(size_t)(jq + 0) * DD + dcol] = (acc[s][u][q * 4 + 0] - ks4.x * x0) * invs2;
                der[(size_t)(jq + 1) * DD + dcol] = (acc[s][u][q * 4 + 1] - ks4.y * x1) * invs2;
                der[(size_t)(jq + 2) * DD + dcol] = (acc[s][u][q * 4 + 2] - ks4.z * x2) * invs2;
                der[(size_t)(jq + 3) * DD + dcol] = (acc[s][u][q * 4 + 3] - ks4.w * x3) * invs2;
            }
        }
    }
}

// ================= mid path (ws >= MID, < FULL): cast + atomic gram =================
__global__ __launch_bounds__(256) void cast_kernel(const float* __restrict__ X,
                                                   unsigned short* __restrict__ XbF,
                                                   unsigned short* __restrict__ XbTF) {
    __shared__ __align__(16) unsigned short tileT[64][72];
    const int i0 = blockIdx.y * 64, d0 = blockIdx.x * 64;
    const int t = threadIdx.x;
    const int il = t >> 2, dl = (t & 3) * 16;

    union { unsigned short u[16]; bf16x8 v8[2]; } bv;
    const float4* src = (const float4*)&X[(size_t)(i0 + il) * DD + d0 + dl];
#pragma unroll
    for (int q = 0; q < 4; q++) {
        float4 v = src[q];
        bv.u[q * 4 + 0] = f2bf(v.x); bv.u[q * 4 + 1] = f2bf(v.y);
        bv.u[q * 4 + 2] = f2bf(v.z); bv.u[q * 4 + 3] = f2bf(v.w);
    }
    const int swc = ((dl >> 4) & 3) << 3;
    const int ilx = il ^ swc;
#pragma unroll
    for (int e = 0; e < 16; e++) tileT[dl + e][ilx] = bv.u[e];
    {
        const int lr_row = il & 31;
        const size_t chunk = (size_t)(((i0 + il) >> 5) * 4096 + ((d0 + dl) >> 4));
        *(bf16x8*)&XbF[chunk * 512 + lr_row * 8]       = bv.v8[0];
        *(bf16x8*)&XbF[chunk * 512 + 256 + lr_row * 8] = bv.v8[1];
    }
    __syncthreads();
    const int lane = t & 63, w = t >> 6;
    const int hl = lane >> 5;
    const int lr = lane & 31;
#pragma unroll
    for (int cc = 0; cc < 2; cc++) {
        int c = w * 2 + cc;
        int db_l = c >> 2, i16_l = c & 3;
        int row = db_l * 32 + lr;
        int icol = (i16_l * 16 + hl * 8) ^ (((row >> 4) & 3) << 3);
        bf16x8 v = *(const bf16x8*)&tileT[row][icol];
        int db_g = (d0 >> 5) + db_l, i16_g = (i0 >> 4) + i16_l;
        *(bf16x8*)&XbTF[(size_t)(db_g * 16 + i16_g) * 512 + lane * 8] = v;
    }
}

__global__ __launch_bounds__(512) void gram_mfma(const unsigned short* __restrict__ XbF,
                                                 float* __restrict__ G) {
    const int t = threadIdx.x;
    const int lane = t & 63, w = t >> 6;
    const int wr = w >> 2, wc = w & 3;
    const int kc0 = blockIdx.x * 64;

    f32x16 acc[4][2] = {};
    const unsigned short* pA[4];
    const unsigned short* pB[2];
#pragma unroll
    for (int s = 0; s < 4; s++)
        pA[s] = &XbF[(size_t)((wr * 4 + s) * 4096 + kc0) * 512 + lane * 8];
#pragma unroll
    for (int u = 0; u < 2; u++)
        pB[u] = &XbF[(size_t)((wc * 2 + u) * 4096 + kc0) * 512 + lane * 8];

#pragma unroll 2
    for (int ks = 0; ks < 64; ks++) {
        bf16x8 a[4], b[2];
#pragma unroll
        for (int s = 0; s < 4; s++) a[s] = *(const bf16x8*)(pA[s] + ks * 512);
#pragma unroll
        for (int u = 0; u < 2; u++) b[u] = *(const bf16x8*)(pB[u] + ks * 512);
#pragma unroll
        for (int s = 0; s < 4; s++)
#pragma unroll
            for (int u = 0; u < 2; u++)
                acc[s][u] = __builtin_amdgcn_mfma_f32_32x32x16_bf16(a[s], b[u], acc[s][u], 0, 0, 0);
    }
    const int hl = lane >> 5, lr = lane & 31;
#pragma unroll
    for (int s = 0; s < 4; s++)
#pragma unroll
        for (int u = 0; u < 2; u++) {
            int jc = wc * 64 + u * 32 + lr;
#pragma unroll
            for (int r = 0; r < 16; r++) {
                int ir = wr * 128 + s * 32 + (r & 3) + 8 * (r >> 2) + 4 * hl;
                atomicAdd(&G[ir * NP + jc], acc[s][u][r]);
            }
        }
}

// ================= fallback fp32 path (ws too small) =================
__global__ __launch_bounds__(256) void gram_kernel(const float* __restrict__ X,
                                                   float* __restrict__ G) {
    __shared__ __align__(16) float As[32][72];
    __shared__ __align__(16) float Bs[32][72];
    const int i0 = blockIdx.x * 64;
    const int j0 = blockIdx.y * 64;
    const int k0 = blockIdx.z * 2048;
    const int t  = threadIdx.x;
    const int tx = t & 15, ty = t >> 4;
    float acc[4][4];
#pragma unroll
    for (int q = 0; q < 4; q++)
#pragma unroll
        for (int r = 0; r < 4; r++) acc[q][r] = 0.f;
    for (int kb = k0; kb < k0 + 2048; kb += 32) {
#pragma unroll
        for (int u = 0; u < 2; u++) {
            int f = t * 2 + u, row = f >> 3, c4 = (f & 7) * 4;
            float4 av = *(const float4*)&X[(size_t)(i0 + row) * DD + kb + c4];
            As[c4 + 0][row] = av.x; As[c4 + 1][row] = av.y;
            As[c4 + 2][row] = av.z; As[c4 + 3][row] = av.w;
            float4 bvv = *(const float4*)&X[(size_t)(j0 + row) * DD + kb + c4];
            Bs[c4 + 0][row] = bvv.x; Bs[c4 + 1][row] = bvv.y;
            Bs[c4 + 2][row] = bvv.z; Bs[c4 + 3][row] = bvv.w;
        }
        __syncthreads();
#pragma unroll
        for (int kk = 0; kk < 32; kk++) {
            float4 a4 = *(const float4*)&As[kk][ty * 4];
            float4 b4 = *(const float4*)&Bs[kk][tx * 4];
            acc[0][0] += a4.x * b4.x; acc[0][1] += a4.x * b4.y;
            acc[0][2] += a4.x * b4.z; acc[0][3] += a4.x * b4.w;
            acc[1][0] += a4.y * b4.x; acc[1][1] += a4.y * b4.y;
            acc[1][2] += a4.y * b4.z; acc[1][3] += a4.y * b4.w;
            acc[2][0] += a4.z * b4.x; acc[2][1] += a4.z * b4.y;
            acc[2][2] += a4.z * b4.z; acc[2][3] += a4.z * b4.w;
            acc[3][0] += a4.w * b4.x; acc[3][1] += a4.w * b4.y;
            acc[3][2] += a4.w * b4.z; acc[3][3] += a4.w * b4.w;
        }
        __syncthreads();
    }
#pragma unroll
    for (int q = 0; q < 4; q++)
#pragma unroll
        for (int r = 0; r < 4; r++)
            atomicAdd(&G[(size_t)(i0 + ty * 4 + q) * NP + j0 + tx * 4 + r], acc[q][r]);
}

__global__ __launch_bounds__(256) void der_kernel(const float* __restrict__ X,
                                                  const float* __restrict__ kmat,
                                                  const float* __restrict__ ksum,
                                                  const float* __restrict__ sig,
                                                  float* __restrict__ der) {
    const int j0 = blockIdx.y * 32;
    const int d0 = blockIdx.x * 512 + threadIdx.x * 2;
    const float invs2 = sig[2];
    float2 acc[32];
#pragma unroll
    for (int jl = 0; jl < 32; jl++) { acc[jl].x = 0.f; acc[jl].y = 0.f; }
    for (int i = 0; i < NP; i++) {
        float2 xv = *(const float2*)&X[(size_t)i * DD + d0];
        const float4* kr = (const float4*)&kmat[i * NP + j0];
#pragma unroll
        for (int q = 0; q < 8; q++) {
            float4 k4 = kr[q];
            acc[q * 4 + 0].x += k4.x * xv.x; acc[q * 4 + 0].y += k4.x * xv.y;
            acc[q * 4 + 1].x += k4.y * xv.x; acc[q * 4 + 1].y += k4.y * xv.y;
            acc[q * 4 + 2].x += k4.z * xv.x; acc[q * 4 + 2].y += k4.z * xv.y;
            acc[q * 4 + 3].x += k4.w * xv.x; acc[q * 4 + 3].y += k4.w * xv.y;
        }
    }
#pragma unroll
    for (int jl = 0; jl < 32; jl++) {
        int j = j0 + jl;
        float2 xj = *(const float2*)&X[(size_t)j * DD + d0];
        float ks = ksum[j];
        float2 o;
        o.x = (acc[jl].x - ks * xj.x) * invs2;
        o.y = (acc[jl].y - ks * xj.y) * invs2;
        *(float2*)&der[(size_t)j * DD + d0] = o;
    }
}

extern "C" void kernel_launch(void* const* d_in, const int* in_sizes, int n_in,
                              void* d_out, int out_size, void* d_ws, size_t ws_size,
                              hipStream_t stream) {
    const float* X   = (const float*)d_in[0];
    const float* EMA = (const float*)d_in[1];
    float* out = (float*)d_out;
    float* ws  = (float*)d_ws;

    float* G    = ws;
    float* sq   = ws + WS_SQ;
    float* ksum = ws + WS_KSUM;
    float* sig  = ws + WS_SIG;

    float* kout      = out;
    float* der       = out + NP * NP;
    float* sigma_out = out + out_size - 1;

    if (ws_size >= (size_t)WS_NEED_FULL) {
        unsigned short* XbTF = (unsigned short*)((char*)d_ws + XBTF_BYTE_OFF);
        unsigned short* kbF  = (unsigned short*)((char*)d_ws + KBF_BYTE_OFF);
        float* P = (float*)((char*)d_ws + PART_BYTE_OFF);

        fused_gram_cast<<<dim3(2, 2, 64), 512, 0, stream>>>(X, P, XbTF);
        gram_reduce<<<64, 256, 0, stream>>>(P, G);
        median_sigma_kernel<<<1, 1024, 0, stream>>>(G, EMA, sq, sig, sigma_out);
        kexp_kernel<<<NP, NP, 0, stream>>>(G, sq, sig, kout, kbF, ksum);
        der_mfma<<<dim3(256, 2), 512, 0, stream>>>(kbF, XbTF, ksum, sig, der);
    } else if (ws_size >= (size_t)WS_NEED_MID) {
        unsigned short* XbF  = (unsigned short*)((char*)d_ws + XBF_BYTE_OFF);
        unsigned short* XbTF = (unsigned short*)((char*)d_ws + XBTF_BYTE_OFF);
        unsigned short* kbF  = (unsigned short*)((char*)d_ws + KBF_BYTE_OFF);

        hipMemsetAsync(G, 0, (size_t)NP * NP * sizeof(float), stream);
        cast_kernel<<<dim3(1024, 4), 256, 0, stream>>>(X, XbF, XbTF);
        gram_mfma<<<64, 512, 0, stream>>>(XbF, G);
        median_sigma_kernel<<<1, 1024, 0, stream>>>(G, EMA, sq, sig, sigma_out);
        kexp_kernel<<<NP, NP, 0, stream>>>(G, sq, sig, kout, kbF, ksum);
        der_mfma<<<dim3(256, 2), 512, 0, stream>>>(kbF, XbTF, ksum, sig, der);
    } else {
        hipMemsetAsync(G, 0, (size_t)NP * NP * sizeof(float), stream);
        gram_kernel<<<dim3(4, 4, 32), 256, 0, stream>>>(X, G);
        median_sigma_kernel<<<1, 1024, 0, stream>>>(G, EMA, sq, sig, sigma_out);
        kexp_kernel<<<NP, NP, 0, stream>>>(G, sq, sig, kout, nullptr, ksum);
        der_kernel<<<dim3(128, 8), 256, 0, stream>>>(X, kout, ksum, sig, der);
    }
}